// Round 1
// baseline (1581.270 us; speedup 1.0000x reference)
//
#include <hip/hip_runtime.h>
#include <hip/hip_bf16.h>
#include <cstdint>
#include <cstddef>

// Problem constants
constexpr int NE  = 64;    // experts
constexpr int DM  = 1024;  // d_model
constexpr int DF  = 2048;  // d_ff
constexpr int CPE = 512;   // tokens per expert

typedef float  f32x4  __attribute__((ext_vector_type(4)));
typedef short  bf16x8 __attribute__((ext_vector_type(8)));

__device__ __forceinline__ short f2bf(float f) {
    union { __hip_bfloat16 h; short s; } u;
    u.h = __float2bfloat16(f);   // RNE
    return u.s;
}

__device__ __forceinline__ float gelu_tanh(float x) {
    // jax.nn.gelu default (approximate=True): 0.5x(1+tanh(sqrt(2/pi)(x+0.044715x^3)))
    float z = 0.7978845608028654f * (x + 0.044715f * x * x * x);
    float e = __expf(2.0f * z);          // z->-inf: e->0 => t=-1 ; z->+inf: e->inf => t=1
    float t = 1.0f - 2.0f / (e + 1.0f);
    return 0.5f * x * (1.0f + t);
}

// Generic per-expert GEMM: C[e] = epilogue(A[e] @ B[e])
//   A: [NE*CPE, KTOT] (fp32 or bf16, row-major)
//   B: [NE, KTOT, NTOT] fp32 row-major (K-major => transpose-cast into LDS)
//   C: [NE*CPE, NTOT]  (bf16 with GELU, or fp32 plain)
// Tile: 128x128 output, BK=32, 256 threads = 2x2 waves, wave does 4x4 MFMA 16x16x32 bf16.
// LDS rows padded to 40 shorts (80 B): 16B-aligned b128 access, <=2-way bank aliasing (free).
template <int KTOT, int NTOT, bool GELU_OUT, bool A_BF16>
__global__ __launch_bounds__(256)
void ffn_gemm(const void* __restrict__ Ag, const float* __restrict__ Bg, void* __restrict__ Cg)
{
    constexpr int BPE = (NTOT / 128) * 4;   // blocks per expert (4 M-tiles)
    const int bid = blockIdx.x;
    const int e   = bid / BPE;
    const int t   = bid % BPE;
    const int mt  = t & 3;     // M-tile index (0..3), fast => 4 blocks share the same B-panel
    const int nt  = t >> 2;    // N-tile index

    __shared__ short As[128 * 40];
    __shared__ short Bs[128 * 40];

    const int tid  = threadIdx.x;
    const int lane = tid & 63;
    const int wave = tid >> 6;
    const int wm   = wave & 1;      // wave row (0..1) -> 64 rows
    const int wn   = wave >> 1;     // wave col (0..1) -> 64 cols

    // A staging: thread covers 16 consecutive k of one row
    const int am = tid >> 1;              // 0..127
    const int ak = (tid & 1) << 4;        // 0 or 16
    // B staging: thread covers 8 consecutive k rows x 2 consecutive n cols
    const int bn = (tid & 63) << 1;       // 0,2,...,126
    const int bk = (tid >> 6) << 3;       // 0,8,16,24

    const size_t arow0 = (size_t)(e * CPE + mt * 128);
    const float* Bge = Bg + (size_t)e * KTOT * NTOT + nt * 128;

    f32x4 acc[4][4];
#pragma unroll
    for (int i = 0; i < 4; ++i)
#pragma unroll
        for (int j = 0; j < 4; ++j) acc[i][j] = f32x4{0.f, 0.f, 0.f, 0.f};

    const int fr = lane & 15;             // fragment row/col within 16
    const int fq = (lane >> 4) << 3;      // quad*8 -> k offset (shorts)

    for (int kk = 0; kk < KTOT; kk += 32) {
        // ---- stage A tile (128 x 32) into As[m][k] ----
        if constexpr (A_BF16) {
            const short* Ab = (const short*)Ag + (arow0 + am) * (size_t)KTOT + kk + ak;
            uint4 v0 = *(const uint4*)(Ab);
            uint4 v1 = *(const uint4*)(Ab + 8);
            *(uint4*)&As[am * 40 + ak]     = v0;
            *(uint4*)&As[am * 40 + ak + 8] = v1;
        } else {
            const float* Af = (const float*)Ag + (arow0 + am) * (size_t)KTOT + kk + ak;
            float4 v0 = *(const float4*)(Af + 0);
            float4 v1 = *(const float4*)(Af + 4);
            float4 v2 = *(const float4*)(Af + 8);
            float4 v3 = *(const float4*)(Af + 12);
            bf16x8 s0, s1;
            s0[0]=f2bf(v0.x); s0[1]=f2bf(v0.y); s0[2]=f2bf(v0.z); s0[3]=f2bf(v0.w);
            s0[4]=f2bf(v1.x); s0[5]=f2bf(v1.y); s0[6]=f2bf(v1.z); s0[7]=f2bf(v1.w);
            s1[0]=f2bf(v2.x); s1[1]=f2bf(v2.y); s1[2]=f2bf(v2.z); s1[3]=f2bf(v2.w);
            s1[4]=f2bf(v3.x); s1[5]=f2bf(v3.y); s1[6]=f2bf(v3.z); s1[7]=f2bf(v3.w);
            *(bf16x8*)&As[am * 40 + ak]     = s0;
            *(bf16x8*)&As[am * 40 + ak + 8] = s1;
        }
        // ---- stage B tile (32 x 128), transposed+cast into Bs[n][k] ----
        {
            const float* pb = Bge + (size_t)(kk + bk) * NTOT + bn;
            float2 bv[8];
#pragma unroll
            for (int j = 0; j < 8; ++j) bv[j] = *(const float2*)(pb + (size_t)j * NTOT);
            bf16x8 s0, s1;
#pragma unroll
            for (int j = 0; j < 8; ++j) { s0[j] = f2bf(bv[j].x); s1[j] = f2bf(bv[j].y); }
            *(bf16x8*)&Bs[(bn + 0) * 40 + bk] = s0;
            *(bf16x8*)&Bs[(bn + 1) * 40 + bk] = s1;
        }
        __syncthreads();

        // ---- fragments + MFMA ----
        bf16x8 af[4], bf[4];
#pragma unroll
        for (int i = 0; i < 4; ++i)
            af[i] = *(const bf16x8*)&As[(wm * 64 + i * 16 + fr) * 40 + fq];
#pragma unroll
        for (int j = 0; j < 4; ++j)
            bf[j] = *(const bf16x8*)&Bs[(wn * 64 + j * 16 + fr) * 40 + fq];
#pragma unroll
        for (int i = 0; i < 4; ++i)
#pragma unroll
            for (int j = 0; j < 4; ++j)
                acc[i][j] = __builtin_amdgcn_mfma_f32_16x16x32_bf16(af[i], bf[j], acc[i][j], 0, 0, 0);
        __syncthreads();
    }

    // ---- epilogue: C/D layout col=lane&15, row=quad*4+reg ----
    const int lr = (lane >> 4) << 2;
    const int lc = lane & 15;
    const size_t crow0 = arow0 + wm * 64;
    const int    ccol0 = nt * 128 + wn * 64;
#pragma unroll
    for (int i = 0; i < 4; ++i) {
#pragma unroll
        for (int r = 0; r < 4; ++r) {
            const size_t row = crow0 + i * 16 + lr + r;
#pragma unroll
            for (int j = 0; j < 4; ++j) {
                float v = acc[i][j][r];
                const size_t idx = row * (size_t)NTOT + ccol0 + j * 16 + lc;
                if constexpr (GELU_OUT) {
                    ((__hip_bfloat16*)Cg)[idx] = __float2bfloat16(gelu_tanh(v));
                } else {
                    ((float*)Cg)[idx] = v;
                }
            }
        }
    }
}

extern "C" void kernel_launch(void* const* d_in, const int* in_sizes, int n_in,
                              void* d_out, int out_size, void* d_ws, size_t ws_size,
                              hipStream_t stream)
{
    const float* X  = (const float*)d_in[0];   // [32768, 1024] fp32
    const float* W1 = (const float*)d_in[1];   // [64, 1024, 2048] fp32
    const float* W2 = (const float*)d_in[2];   // [64, 2048, 1024] fp32
    float*       Y  = (float*)d_out;           // [32768, 1024] fp32

    // ws: H = gelu(X@W1) as bf16, [32768, 2048] = 134,217,728 bytes
    __hip_bfloat16* H = (__hip_bfloat16*)d_ws;

    // GEMM1: H = gelu(X @ W1); grid = 64 experts * 4 M-tiles * 16 N-tiles
    ffn_gemm<DM, DF, true, false><<<dim3(NE * 64), dim3(256), 0, stream>>>(
        (const void*)X, W1, (void*)H);

    // GEMM2: Y = H @ W2; grid = 64 experts * 4 M-tiles * 8 N-tiles
    ffn_gemm<DF, DM, false, true><<<dim3(NE * 32), dim3(256), 0, stream>>>(
        (const void*)H, W2, (void*)Y);
}